// Round 1
// baseline (309.978 us; speedup 1.0000x reference)
//
#include <hip/hip_runtime.h>

// Problem dims (fixed by reference): B=8, L=4096, K=32, C=64, KC=2048
#define B_DIM 8
#define L_DIM 4096
#define KC 2048              // K*C, contiguous innermost span per (b,l)
#define LBLK 32              // l-rows per reduce block  -> 8*128 = 1024 blocks
#define LCB  32              // l-rows per bcast block   -> 1024 blocks
#define NTHREADS 256         // each thread owns 8 contiguous (k,c) slots

// ws layout: [0, B*KC)            fp32 sums
//            [B*KC, 2*B*KC)       fp32 counts (exact: integer-valued, < 2^24)
#define WS_FLOATS (2 * B_DIM * KC)

__global__ __launch_bounds__(256) void zero_ws_k(float* __restrict__ ws) {
    int i = blockIdx.x * 256 + threadIdx.x;
    if (i < WS_FLOATS) ws[i] = 0.0f;
}

__global__ __launch_bounds__(256) void reduce_k(const float* __restrict__ x,
                                                const int* __restrict__ mask,
                                                float* __restrict__ ws) {
    const int blocks_per_b = L_DIM / LBLK;          // 128
    const int b    = blockIdx.x / blocks_per_b;
    const int lseg = blockIdx.x % blocks_per_b;
    const int t    = threadIdx.x;

    // base element index of this thread's first slot at l = lseg*LBLK
    const long base = ((long)b * L_DIM + (long)lseg * LBLK) * KC + t * 8;

    float s[8] = {0.f, 0.f, 0.f, 0.f, 0.f, 0.f, 0.f, 0.f};
    float c[8] = {0.f, 0.f, 0.f, 0.f, 0.f, 0.f, 0.f, 0.f};

    for (int l = 0; l < LBLK; ++l) {
        const float* xr = x    + base + (long)l * KC;
        const int*   mr = mask + base + (long)l * KC;
        float4 xv0 = *(const float4*)(xr);
        float4 xv1 = *(const float4*)(xr + 4);
        int4   mv0 = *(const int4*)(mr);
        int4   mv1 = *(const int4*)(mr + 4);

        float xf[8] = {xv0.x, xv0.y, xv0.z, xv0.w, xv1.x, xv1.y, xv1.z, xv1.w};
        int   mi[8] = {mv0.x, mv0.y, mv0.z, mv0.w, mv1.x, mv1.y, mv1.z, mv1.w};
        #pragma unroll
        for (int j = 0; j < 8; ++j) {
            float mf = (float)mi[j];
            s[j] = fmaf(xf[j], mf, s[j]);
            c[j] += mf;
        }
    }

    float* sum_ws = ws + (long)b * KC + t * 8;
    float* cnt_ws = ws + (long)B_DIM * KC + (long)b * KC + t * 8;
    #pragma unroll
    for (int j = 0; j < 8; ++j) {
        atomicAdd(&sum_ws[j], s[j]);
        atomicAdd(&cnt_ws[j], c[j]);
    }
}

__global__ __launch_bounds__(256) void bcast_k(const float* __restrict__ ws,
                                               float* __restrict__ out) {
    __shared__ float mean[KC];
    const int blocks_per_b = L_DIM / LCB;           // 128
    const int b    = blockIdx.x / blocks_per_b;
    const int lseg = blockIdx.x % blocks_per_b;
    const int t    = threadIdx.x;

    #pragma unroll
    for (int j = t; j < KC; j += NTHREADS) {
        float s  = ws[(long)b * KC + j];
        float cn = ws[(long)B_DIM * KC + (long)b * KC + j];
        mean[j] = (cn > 0.f) ? (s / cn) : 0.f;
    }
    __syncthreads();

    float4 v0 = *(const float4*)(&mean[t * 8]);
    float4 v1 = *(const float4*)(&mean[t * 8 + 4]);

    const long base = ((long)b * L_DIM + (long)lseg * LCB) * KC + t * 8;
    for (int l = 0; l < LCB; ++l) {
        float* orow = out + base + (long)l * KC;
        *(float4*)(orow)     = v0;
        *(float4*)(orow + 4) = v1;
    }
}

extern "C" void kernel_launch(void* const* d_in, const int* in_sizes, int n_in,
                              void* d_out, int out_size, void* d_ws, size_t ws_size,
                              hipStream_t stream) {
    const float* x    = (const float*)d_in[0];
    const int*   mask = (const int*)d_in[1];
    float*       out  = (float*)d_out;
    float*       ws   = (float*)d_ws;

    // 1) zero accumulators (d_ws is poisoned once and never re-poisoned)
    zero_ws_k<<<(WS_FLOATS + 255) / 256, 256, 0, stream>>>(ws);

    // 2) masked sum + count reduction over L
    reduce_k<<<B_DIM * (L_DIM / LBLK), NTHREADS, 0, stream>>>(x, mask, ws);

    // 3) finalize mean + broadcast to [B, L, K, C]
    bcast_k<<<B_DIM * (L_DIM / LCB), NTHREADS, 0, stream>>>(ws, out);
}

// Round 2
// 214.917 us; speedup vs baseline: 1.4423x; 1.4423x over previous
//
#include <hip/hip_runtime.h>

// Problem dims (fixed by reference): B=8, L=4096, K=32, C=64, KC=2048
#define B_DIM 8
#define L_DIM 4096
#define KC 2048              // K*C, contiguous innermost span per (b,l)
#define LCB  32              // l-rows per bcast block -> 1024 blocks
#define NTHREADS 256         // each thread owns 8 contiguous (k,c) slots

// ---------------------------------------------------------------------------
// Stage 1: per-(b,segment) private partial sums/counts. No atomics.
// psum[(b*nseg + seg)*KC + j], pcnt likewise. Plain coalesced stores.
// ---------------------------------------------------------------------------
__global__ __launch_bounds__(256) void partial_k(const float* __restrict__ x,
                                                 const int* __restrict__ mask,
                                                 float* __restrict__ psum,
                                                 float* __restrict__ pcnt,
                                                 int nseg, int lrows) {
    const int b   = blockIdx.x / nseg;
    const int seg = blockIdx.x % nseg;
    const int t   = threadIdx.x;

    const long base = ((long)b * L_DIM + (long)seg * lrows) * KC + t * 8;

    float s[8] = {0.f, 0.f, 0.f, 0.f, 0.f, 0.f, 0.f, 0.f};
    float c[8] = {0.f, 0.f, 0.f, 0.f, 0.f, 0.f, 0.f, 0.f};

    for (int l = 0; l < lrows; ++l) {
        const float* xr = x    + base + (long)l * KC;
        const int*   mr = mask + base + (long)l * KC;
        float4 xv0 = *(const float4*)(xr);
        float4 xv1 = *(const float4*)(xr + 4);
        int4   mv0 = *(const int4*)(mr);
        int4   mv1 = *(const int4*)(mr + 4);

        float xf[8] = {xv0.x, xv0.y, xv0.z, xv0.w, xv1.x, xv1.y, xv1.z, xv1.w};
        int   mi[8] = {mv0.x, mv0.y, mv0.z, mv0.w, mv1.x, mv1.y, mv1.z, mv1.w};
        #pragma unroll
        for (int j = 0; j < 8; ++j) {
            float mf = (float)mi[j];
            s[j] = fmaf(xf[j], mf, s[j]);
            c[j] += mf;
        }
    }

    const long po = ((long)b * nseg + seg) * KC + t * 8;
    *(float4*)(&psum[po])     = make_float4(s[0], s[1], s[2], s[3]);
    *(float4*)(&psum[po + 4]) = make_float4(s[4], s[5], s[6], s[7]);
    *(float4*)(&pcnt[po])     = make_float4(c[0], c[1], c[2], c[3]);
    *(float4*)(&pcnt[po + 4]) = make_float4(c[4], c[5], c[6], c[7]);
}

// ---------------------------------------------------------------------------
// Stage 2: fold nseg partials per (b,j), finalize mean. B*KC = 16384 threads.
// ---------------------------------------------------------------------------
__global__ __launch_bounds__(256) void mean_k(const float* __restrict__ psum,
                                              const float* __restrict__ pcnt,
                                              float* __restrict__ mean,
                                              int nseg) {
    const int i = blockIdx.x * 256 + threadIdx.x;   // 0 .. B*KC-1
    const int b = i / KC;
    const int j = i % KC;

    float s = 0.f, c = 0.f;
    for (int seg = 0; seg < nseg; ++seg) {
        const long o = ((long)b * nseg + seg) * KC + j;
        s += psum[o];
        c += pcnt[o];
    }
    mean[i] = (c > 0.f) ? (s / c) : 0.f;
}

// ---------------------------------------------------------------------------
// Stage 3: broadcast mean[b,:,:] to all L rows. Pure coalesced float4 stores.
// ---------------------------------------------------------------------------
__global__ __launch_bounds__(256) void bcast_k(const float* __restrict__ mean,
                                               float* __restrict__ out) {
    __shared__ float m_lds[KC];
    const int blocks_per_b = L_DIM / LCB;           // 128
    const int b    = blockIdx.x / blocks_per_b;
    const int lseg = blockIdx.x % blocks_per_b;
    const int t    = threadIdx.x;

    #pragma unroll
    for (int j = t; j < KC; j += NTHREADS)
        m_lds[j] = mean[(long)b * KC + j];
    __syncthreads();

    float4 v0 = *(const float4*)(&m_lds[t * 8]);
    float4 v1 = *(const float4*)(&m_lds[t * 8 + 4]);

    const long base = ((long)b * L_DIM + (long)lseg * LCB) * KC + t * 8;
    for (int l = 0; l < LCB; ++l) {
        float* orow = out + base + (long)l * KC;
        *(float4*)(orow)     = v0;
        *(float4*)(orow + 4) = v1;
    }
}

extern "C" void kernel_launch(void* const* d_in, const int* in_sizes, int n_in,
                              void* d_out, int out_size, void* d_ws, size_t ws_size,
                              hipStream_t stream) {
    const float* x    = (const float*)d_in[0];
    const int*   mask = (const int*)d_in[1];
    float*       out  = (float*)d_out;
    float*       ws   = (float*)d_ws;

    // Pick the largest nseg (parallelism over L) whose partials fit in ws.
    // Need (2*B*nseg*KC + B*KC) * 4 bytes. Deterministic for fixed ws_size.
    int nseg = 128;
    while (nseg > 1 &&
           (size_t)(2ul * B_DIM * nseg * KC + B_DIM * KC) * 4ul > ws_size)
        nseg >>= 1;
    const int lrows = L_DIM / nseg;

    float* psum = ws;
    float* pcnt = ws + (long)B_DIM * nseg * KC;
    float* mean = ws + 2l * B_DIM * nseg * KC;

    // 1) private partial sums/counts (no atomics)
    partial_k<<<B_DIM * nseg, NTHREADS, 0, stream>>>(x, mask, psum, pcnt,
                                                     nseg, lrows);

    // 2) fold partials, finalize mean
    mean_k<<<(B_DIM * KC) / 256, 256, 0, stream>>>(psum, pcnt, mean, nseg);

    // 3) broadcast to [B, L, K, C]
    bcast_k<<<B_DIM * (L_DIM / LCB), NTHREADS, 0, stream>>>(mean, out);
}

// Round 3
// 196.183 us; speedup vs baseline: 1.5800x; 1.0955x over previous
//
#include <hip/hip_runtime.h>

// Problem dims (fixed by reference): B=8, L=4096, K=32, C=64, KC=2048
#define B_DIM 8
#define L_DIM 4096
#define KC 2048              // K*C, contiguous innermost span per (b,l)
#define LCB  16              // l-rows per bcast block -> 2048 blocks
#define PT   512             // partial_k threads: one float4 column each

// ---------------------------------------------------------------------------
// Stage 1: per-(b,segment) private partial sums/counts. No atomics.
// 512 threads/block, thread t owns float4 column t (bytes 16t..16t+15 of each
// row) -> every wave-wide load instruction covers a contiguous 1 KB segment.
// unroll 4 -> 8 independent 16B loads in flight per thread.
// ---------------------------------------------------------------------------
__global__ __launch_bounds__(PT) void partial_k(const float* __restrict__ x,
                                                const int* __restrict__ mask,
                                                float* __restrict__ psum,
                                                float* __restrict__ pcnt,
                                                int nseg, int lrows) {
    const int b   = blockIdx.x / nseg;
    const int seg = blockIdx.x % nseg;
    const int t   = threadIdx.x;

    const long base = ((long)b * L_DIM + (long)seg * lrows) * KC + t * 4;

    float4 s = make_float4(0.f, 0.f, 0.f, 0.f);
    float4 c = make_float4(0.f, 0.f, 0.f, 0.f);

    #pragma unroll 4
    for (int l = 0; l < lrows; ++l) {
        const float4 xv = *(const float4*)(x    + base + (long)l * KC);
        const int4   mv = *(const int4*)  (mask + base + (long)l * KC);
        float m0 = (float)mv.x, m1 = (float)mv.y, m2 = (float)mv.z, m3 = (float)mv.w;
        s.x = fmaf(xv.x, m0, s.x);  c.x += m0;
        s.y = fmaf(xv.y, m1, s.y);  c.y += m1;
        s.z = fmaf(xv.z, m2, s.z);  c.z += m2;
        s.w = fmaf(xv.w, m3, s.w);  c.w += m3;
    }

    const long po = ((long)b * nseg + seg) * KC + t * 4;
    *(float4*)(&psum[po]) = s;
    *(float4*)(&pcnt[po]) = c;
}

// ---------------------------------------------------------------------------
// Stage 2: fold nseg partials per (b,j), finalize mean. B*KC = 16384 threads.
// ---------------------------------------------------------------------------
__global__ __launch_bounds__(256) void mean_k(const float* __restrict__ psum,
                                              const float* __restrict__ pcnt,
                                              float* __restrict__ mean,
                                              int nseg) {
    const int i = blockIdx.x * 256 + threadIdx.x;   // 0 .. B*KC-1
    const int b = i / KC;
    const int j = i % KC;

    float s = 0.f, c = 0.f;
    #pragma unroll 4
    for (int seg = 0; seg < nseg; ++seg) {
        const long o = ((long)b * nseg + seg) * KC + j;
        s += psum[o];
        c += pcnt[o];
    }
    mean[i] = (c > 0.f) ? (s / c) : 0.f;
}

// ---------------------------------------------------------------------------
// Stage 3: broadcast mean[b,:,:] to all L rows. mean is 64 KB -> L2-resident;
// skip LDS, read the thread's float4 once and stream stores.
// ---------------------------------------------------------------------------
__global__ __launch_bounds__(PT) void bcast_k(const float* __restrict__ mean,
                                              float* __restrict__ out) {
    const int blocks_per_b = L_DIM / LCB;           // 256
    const int b    = blockIdx.x / blocks_per_b;
    const int lseg = blockIdx.x % blocks_per_b;
    const int t    = threadIdx.x;

    const float4 v = *(const float4*)(&mean[(long)b * KC + t * 4]);

    const long base = ((long)b * L_DIM + (long)lseg * LCB) * KC + t * 4;
    #pragma unroll
    for (int l = 0; l < LCB; ++l)
        *(float4*)(out + base + (long)l * KC) = v;
}

extern "C" void kernel_launch(void* const* d_in, const int* in_sizes, int n_in,
                              void* d_out, int out_size, void* d_ws, size_t ws_size,
                              hipStream_t stream) {
    const float* x    = (const float*)d_in[0];
    const int*   mask = (const int*)d_in[1];
    float*       out  = (float*)d_out;
    float*       ws   = (float*)d_ws;

    // Largest nseg whose partials fit in ws: (2*B*nseg*KC + B*KC)*4 bytes.
    // Deterministic for fixed ws_size. nseg=128 measured to fit (R1).
    int nseg = 128;
    while (nseg > 1 &&
           (size_t)(2ul * B_DIM * nseg * KC + B_DIM * KC) * 4ul > ws_size)
        nseg >>= 1;
    const int lrows = L_DIM / nseg;

    float* psum = ws;
    float* pcnt = ws + (long)B_DIM * nseg * KC;
    float* mean = ws + 2l * B_DIM * nseg * KC;

    // 1) private partial sums/counts (no atomics), full occupancy
    partial_k<<<B_DIM * nseg, PT, 0, stream>>>(x, mask, psum, pcnt,
                                               nseg, lrows);

    // 2) fold partials, finalize mean
    mean_k<<<(B_DIM * KC) / 256, 256, 0, stream>>>(psum, pcnt, mean, nseg);

    // 3) broadcast to [B, L, K, C]
    bcast_k<<<B_DIM * (L_DIM / LCB), PT, 0, stream>>>(mean, out);
}